// Round 1
// baseline (62.932 us; speedup 1.0000x reference)
//
#include <hip/hip_runtime.h>
#include <math.h>

#define BB 16
#define KK 5
#define NN 4096
#define DD 1024
#define TOPK 9
#define EPSV 1e-12f
#define RPB 64   // patch rows per block in sims kernel

// ---------------- kernel 1: normalize cue rows ----------------
// grid = B*K blocks, 256 threads; each thread owns one float4 of the row.
__global__ __launch_bounds__(256) void norm_cue_kernel(
    const float* __restrict__ cue, float* __restrict__ cue_n) {
  int row = blockIdx.x;  // 0..B*K
  const float4* src = (const float4*)(cue + (size_t)row * DD);
  float4 v = src[threadIdx.x];
  float s = v.x * v.x + v.y * v.y + v.z * v.z + v.w * v.w;
#pragma unroll
  for (int off = 32; off; off >>= 1) s += __shfl_xor(s, off, 64);
  __shared__ float red[4];
  int wid = threadIdx.x >> 6;
  if ((threadIdx.x & 63) == 0) red[wid] = s;
  __syncthreads();
  float tot = red[0] + red[1] + red[2] + red[3];
  float inv = 1.0f / fmaxf(sqrtf(tot), EPSV);
  float4 o;
  o.x = v.x * inv; o.y = v.y * inv; o.z = v.z * inv; o.w = v.w * inv;
  ((float4*)(cue_n + (size_t)row * DD))[threadIdx.x] = o;
}

// ---------------- kernel 2: sims + patch inv-norms (memory-bound) -------
// grid = (N/RPB, B), 256 threads = 4 waves. Each wave handles one patch row
// at a time: 64 lanes x 4 float4 = 1024 floats. Cue fragments live in VGPRs.
__global__ __launch_bounds__(256) void sims_kernel(
    const float* __restrict__ patches, const float* __restrict__ cue_n,
    float* __restrict__ sims, float* __restrict__ invn) {
  int b = blockIdx.y;
  int row0 = blockIdx.x * RPB;
  int wid = threadIdx.x >> 6;
  int lane = threadIdx.x & 63;

  // load this lane's cue fragments: 5 cues x 4 float4 = 80 VGPRs
  float4 c[KK][4];
  const float4* cb = (const float4*)(cue_n + (size_t)b * KK * DD);
#pragma unroll
  for (int k = 0; k < KK; ++k)
#pragma unroll
    for (int j = 0; j < 4; ++j)
      c[k][j] = cb[k * 256 + j * 64 + lane];

  const float4* pb = (const float4*)(patches + (size_t)b * NN * DD);

  for (int r = wid; r < RPB; r += 4) {
    int row = row0 + r;
    const float4* p4 = pb + (size_t)row * 256;
    float acc0 = 0.f, acc1 = 0.f, acc2 = 0.f, acc3 = 0.f, acc4 = 0.f;
    float nr = 0.f;
#pragma unroll
    for (int j = 0; j < 4; ++j) {
      float4 p = p4[j * 64 + lane];
      nr += p.x * p.x + p.y * p.y + p.z * p.z + p.w * p.w;
      acc0 += p.x * c[0][j].x + p.y * c[0][j].y + p.z * c[0][j].z + p.w * c[0][j].w;
      acc1 += p.x * c[1][j].x + p.y * c[1][j].y + p.z * c[1][j].z + p.w * c[1][j].w;
      acc2 += p.x * c[2][j].x + p.y * c[2][j].y + p.z * c[2][j].z + p.w * c[2][j].w;
      acc3 += p.x * c[3][j].x + p.y * c[3][j].y + p.z * c[3][j].z + p.w * c[3][j].w;
      acc4 += p.x * c[4][j].x + p.y * c[4][j].y + p.z * c[4][j].z + p.w * c[4][j].w;
    }
#pragma unroll
    for (int off = 32; off; off >>= 1) {
      nr   += __shfl_xor(nr,   off, 64);
      acc0 += __shfl_xor(acc0, off, 64);
      acc1 += __shfl_xor(acc1, off, 64);
      acc2 += __shfl_xor(acc2, off, 64);
      acc3 += __shfl_xor(acc3, off, 64);
      acc4 += __shfl_xor(acc4, off, 64);
    }
    if (lane == 0) {
      float inv = 1.0f / fmaxf(sqrtf(nr), EPSV);
      invn[b * NN + row] = inv;
      sims[((size_t)b * KK + 0) * NN + row] = acc0 * inv;
      sims[((size_t)b * KK + 1) * NN + row] = acc1 * inv;
      sims[((size_t)b * KK + 2) * NN + row] = acc2 * inv;
      sims[((size_t)b * KK + 3) * NN + row] = acc3 * inv;
      sims[((size_t)b * KK + 4) * NN + row] = acc4 * inv;
    }
  }
}

// ---------------- kernel 3: top-9 + gather-mean ----------------
// grid = B*K blocks, 256 threads. Sims row in LDS, 9 argmax extractions
// (tie-break: smaller index, matching jax.lax.top_k), then gather 9 rows
// with all loads in flight.
__global__ __launch_bounds__(256) void topk_gather_kernel(
    const float* __restrict__ patches, const float* __restrict__ sims,
    const float* __restrict__ invn, float* __restrict__ out) {
  int bk = blockIdx.x;  // 0..B*K
  int b = bk / KK;
  __shared__ float s[NN];
  __shared__ unsigned long long redu[4];
  __shared__ int sel_idx[TOPK];
  __shared__ float sel_inv[TOPK];

  const float4* srow = (const float4*)(sims + (size_t)bk * NN);
#pragma unroll
  for (int j = 0; j < 4; ++j)
    ((float4*)s)[j * 256 + threadIdx.x] = srow[j * 256 + threadIdx.x];
  __syncthreads();

  int wid = threadIdx.x >> 6, lane = threadIdx.x & 63;
  for (int it = 0; it < TOPK; ++it) {
    unsigned long long best = 0ull;
#pragma unroll
    for (int j = 0; j < 16; ++j) {
      int idx = j * 256 + threadIdx.x;
      float v = s[idx];
      unsigned u = __float_as_uint(v);
      u = (u & 0x80000000u) ? ~u : (u | 0x80000000u);
      unsigned long long key =
          ((unsigned long long)u << 32) | (unsigned)(~idx);
      best = key > best ? key : best;
    }
#pragma unroll
    for (int off = 32; off; off >>= 1) {
      unsigned long long o = __shfl_xor(best, off, 64);
      best = o > best ? o : best;
    }
    if (lane == 0) redu[wid] = best;
    __syncthreads();
    if (threadIdx.x == 0) {
      unsigned long long m = redu[0];
      for (int w = 1; w < 4; ++w) m = redu[w] > m ? redu[w] : m;
      int idx = (int)(~(unsigned)(m & 0xFFFFFFFFu));
      sel_idx[it] = idx;
      sel_inv[it] = invn[b * NN + idx];
      s[idx] = -INFINITY;  // exclude from later iterations
    }
    __syncthreads();
  }

  // gather: each thread accumulates one float4 column chunk across the 9 rows
  const float4* pb = (const float4*)(patches + (size_t)b * NN * DD);
  float4 acc; acc.x = acc.y = acc.z = acc.w = 0.f;
#pragma unroll
  for (int it = 0; it < TOPK; ++it) {
    float inv = sel_inv[it];
    float4 p = pb[(size_t)sel_idx[it] * 256 + threadIdx.x];
    acc.x += p.x * inv; acc.y += p.y * inv;
    acc.z += p.z * inv; acc.w += p.w * inv;
  }
  const float inv9 = 1.0f / 9.0f;
  float4 o;
  o.x = acc.x * inv9; o.y = acc.y * inv9;
  o.z = acc.z * inv9; o.w = acc.w * inv9;
  ((float4*)(out + (size_t)bk * DD))[threadIdx.x] = o;
}

extern "C" void kernel_launch(void* const* d_in, const int* in_sizes, int n_in,
                              void* d_out, int out_size, void* d_ws, size_t ws_size,
                              hipStream_t stream) {
  const float* cue = (const float*)d_in[0];      // (B, K, D) f32
  const float* patches = (const float*)d_in[1];  // (B, N, D) f32
  float* out = (float*)d_out;                    // (B, K, D) f32

  // workspace layout (floats)
  float* cue_n = (float*)d_ws;                        // B*K*D   = 81920
  float* invn  = cue_n + (size_t)BB * KK * DD;        // B*N     = 65536
  float* sims  = invn + (size_t)BB * NN;              // B*K*N   = 327680

  norm_cue_kernel<<<BB * KK, 256, 0, stream>>>(cue, cue_n);
  dim3 g2(NN / RPB, BB);
  sims_kernel<<<g2, 256, 0, stream>>>(patches, cue_n, sims, invn);
  topk_gather_kernel<<<BB * KK, 256, 0, stream>>>(patches, sims, invn, out);
}

// Round 2
// 60.614 us; speedup vs baseline: 1.0383x; 1.0383x over previous
//
#include <hip/hip_runtime.h>
#include <math.h>

#define BB 16
#define KK 5
#define NN 4096
#define DD 1024
#define TOPK 9
#define EPSV 1e-12f
#define RPB 64   // patch rows per block in sims kernel

// ---------------- kernel A: fused cue-norm + sims + patch inv-norms -------
// grid = (N/RPB, B), 256 threads = 4 waves. Each wave normalizes its
// register-resident cue fragments once, then handles one patch row at a
// time: 64 lanes x 4 float4 = 1024 floats.
__global__ __launch_bounds__(256) void sims_kernel(
    const float* __restrict__ patches, const float* __restrict__ cue,
    float* __restrict__ sims, float* __restrict__ invn) {
  int b = blockIdx.y;
  int row0 = blockIdx.x * RPB;
  int wid = threadIdx.x >> 6;
  int lane = threadIdx.x & 63;

  // load this lane's cue fragments: 5 cues x 4 float4 = 80 VGPRs
  float4 c[KK][4];
  const float4* cb = (const float4*)(cue + (size_t)b * KK * DD);
#pragma unroll
  for (int k = 0; k < KK; ++k)
#pragma unroll
    for (int j = 0; j < 4; ++j)
      c[k][j] = cb[k * 256 + j * 64 + lane];

  // normalize cues fully in-register (each wave redundantly; no syncs)
#pragma unroll
  for (int k = 0; k < KK; ++k) {
    float s = 0.f;
#pragma unroll
    for (int j = 0; j < 4; ++j)
      s += c[k][j].x * c[k][j].x + c[k][j].y * c[k][j].y +
           c[k][j].z * c[k][j].z + c[k][j].w * c[k][j].w;
#pragma unroll
    for (int off = 32; off; off >>= 1) s += __shfl_xor(s, off, 64);
    float inv = 1.0f / fmaxf(sqrtf(s), EPSV);
#pragma unroll
    for (int j = 0; j < 4; ++j) {
      c[k][j].x *= inv; c[k][j].y *= inv;
      c[k][j].z *= inv; c[k][j].w *= inv;
    }
  }

  const float4* pb = (const float4*)(patches + (size_t)b * NN * DD);

#pragma unroll 2
  for (int r = wid; r < RPB; r += 4) {
    int row = row0 + r;
    const float4* p4 = pb + (size_t)row * 256;
    float acc0 = 0.f, acc1 = 0.f, acc2 = 0.f, acc3 = 0.f, acc4 = 0.f;
    float nr = 0.f;
#pragma unroll
    for (int j = 0; j < 4; ++j) {
      float4 p = p4[j * 64 + lane];
      nr += p.x * p.x + p.y * p.y + p.z * p.z + p.w * p.w;
      acc0 += p.x * c[0][j].x + p.y * c[0][j].y + p.z * c[0][j].z + p.w * c[0][j].w;
      acc1 += p.x * c[1][j].x + p.y * c[1][j].y + p.z * c[1][j].z + p.w * c[1][j].w;
      acc2 += p.x * c[2][j].x + p.y * c[2][j].y + p.z * c[2][j].z + p.w * c[2][j].w;
      acc3 += p.x * c[3][j].x + p.y * c[3][j].y + p.z * c[3][j].z + p.w * c[3][j].w;
      acc4 += p.x * c[4][j].x + p.y * c[4][j].y + p.z * c[4][j].z + p.w * c[4][j].w;
    }
#pragma unroll
    for (int off = 32; off; off >>= 1) {
      nr   += __shfl_xor(nr,   off, 64);
      acc0 += __shfl_xor(acc0, off, 64);
      acc1 += __shfl_xor(acc1, off, 64);
      acc2 += __shfl_xor(acc2, off, 64);
      acc3 += __shfl_xor(acc3, off, 64);
      acc4 += __shfl_xor(acc4, off, 64);
    }
    if (lane == 0) {
      float inv = 1.0f / fmaxf(sqrtf(nr), EPSV);
      invn[b * NN + row] = inv;
      sims[((size_t)b * KK + 0) * NN + row] = acc0 * inv;
      sims[((size_t)b * KK + 1) * NN + row] = acc1 * inv;
      sims[((size_t)b * KK + 2) * NN + row] = acc2 * inv;
      sims[((size_t)b * KK + 3) * NN + row] = acc3 * inv;
      sims[((size_t)b * KK + 4) * NN + row] = acc4 * inv;
    }
  }
}

// ---------------- kernel B: register top-9 + gather-mean ----------------
// grid = B*K blocks, 256 threads = 4 waves. Each wave holds 1024 sims in
// 16 packed u64 keys/thread; 9 iterations of {local max, 6-step butterfly,
// invalidate} with NO syncthreads; then a 36->9 merge in wave 0; then the
// gather with all 9 row-loads in flight.
__global__ __launch_bounds__(256) void topk_gather_kernel(
    const float* __restrict__ patches, const float* __restrict__ sims,
    const float* __restrict__ invn, float* __restrict__ out) {
  int bk = blockIdx.x;  // 0..B*K
  int b = bk / KK;
  int wid = threadIdx.x >> 6, lane = threadIdx.x & 63;

  // load the sims row into packed keys: (mapped_f32 << 32) | ~idx
  unsigned long long key[16];
  const float4* srow = (const float4*)(sims + (size_t)bk * NN);
#pragma unroll
  for (int j = 0; j < 4; ++j) {
    float4 v = srow[j * 256 + threadIdx.x];
    int base = 4 * (j * 256 + threadIdx.x);
    float vv[4] = {v.x, v.y, v.z, v.w};
#pragma unroll
    for (int e = 0; e < 4; ++e) {
      unsigned u = __float_as_uint(vv[e]);
      u = (u & 0x80000000u) ? ~u : (u | 0x80000000u);
      key[j * 4 + e] =
          ((unsigned long long)u << 32) | (unsigned)(~(base + e));
    }
  }

  // per-wave top-9 (register-only, no block syncs)
  unsigned long long win[TOPK];
#pragma unroll
  for (int it = 0; it < TOPK; ++it) {
    unsigned long long m = key[0];
#pragma unroll
    for (int j = 1; j < 16; ++j) m = key[j] > m ? key[j] : m;
#pragma unroll
    for (int off = 32; off; off >>= 1) {
      unsigned long long o = __shfl_xor(m, off, 64);
      m = o > m ? o : m;
    }
    win[it] = m;
#pragma unroll
    for (int j = 0; j < 16; ++j)
      if (key[j] == m) key[j] = 0ull;
  }

  __shared__ unsigned long long cand[4 * TOPK];
  __shared__ int sel_idx[TOPK];
  __shared__ float sel_inv[TOPK];
  if (lane == 0) {
#pragma unroll
    for (int it = 0; it < TOPK; ++it) cand[wid * TOPK + it] = win[it];
  }
  __syncthreads();

  // wave 0 merges the 36 candidates -> global top-9
  if (wid == 0) {
    unsigned long long k2 = (lane < 4 * TOPK) ? cand[lane] : 0ull;
    unsigned long long mm[TOPK];
#pragma unroll
    for (int it = 0; it < TOPK; ++it) {
      unsigned long long m = k2;
#pragma unroll
      for (int off = 32; off; off >>= 1) {
        unsigned long long o = __shfl_xor(m, off, 64);
        m = o > m ? o : m;
      }
      mm[it] = m;
      if (k2 == m) k2 = 0ull;
    }
    if (lane == 0) {
#pragma unroll
      for (int it = 0; it < TOPK; ++it) {
        int idx = (int)(~(unsigned)(mm[it] & 0xFFFFFFFFu));
        sel_idx[it] = idx;
        sel_inv[it] = invn[b * NN + idx];  // 9 independent loads in flight
      }
    }
  }
  __syncthreads();

  // gather: each thread accumulates one float4 column chunk across 9 rows
  const float4* pb = (const float4*)(patches + (size_t)b * NN * DD);
  float4 acc; acc.x = acc.y = acc.z = acc.w = 0.f;
#pragma unroll
  for (int it = 0; it < TOPK; ++it) {
    float inv = sel_inv[it];
    float4 p = pb[(size_t)sel_idx[it] * 256 + threadIdx.x];
    acc.x += p.x * inv; acc.y += p.y * inv;
    acc.z += p.z * inv; acc.w += p.w * inv;
  }
  const float inv9 = 1.0f / 9.0f;
  float4 o;
  o.x = acc.x * inv9; o.y = acc.y * inv9;
  o.z = acc.z * inv9; o.w = acc.w * inv9;
  ((float4*)(out + (size_t)bk * DD))[threadIdx.x] = o;
}

extern "C" void kernel_launch(void* const* d_in, const int* in_sizes, int n_in,
                              void* d_out, int out_size, void* d_ws, size_t ws_size,
                              hipStream_t stream) {
  const float* cue = (const float*)d_in[0];      // (B, K, D) f32
  const float* patches = (const float*)d_in[1];  // (B, N, D) f32
  float* out = (float*)d_out;                    // (B, K, D) f32

  // workspace layout (floats)
  float* invn = (float*)d_ws;                    // B*N   = 65536
  float* sims = invn + (size_t)BB * NN;          // B*K*N = 327680

  dim3 g2(NN / RPB, BB);
  sims_kernel<<<g2, 256, 0, stream>>>(patches, cue, sims, invn);
  topk_gather_kernel<<<BB * KK, 256, 0, stream>>>(patches, sims, invn, out);
}